// Round 1
// baseline (8820.824 us; speedup 1.0000x reference)
//
#include <hip/hip_runtime.h>
#include <stdint.h>

#define TT    512
#define HID   1024
#define G4    4096
#define INDIM 85
#define NOUT  20670   // 6890*3
#define CHK   32      // ih-GEMM chunk length in timesteps (must divide TT, power of 2)

typedef unsigned long long u64;

// ---------------------------------------------------------------------------
// Tiled fp32 GEMM: C[M,N] = A[M,K] * B[N,K]^T + bias0 + bias1
// 64x64 tile, BK=16, 256 threads, 4x4 micro-tile per thread. (unchanged)
// ---------------------------------------------------------------------------
__global__ __launch_bounds__(256)
void gemm_nt(const float* __restrict__ A, const float* __restrict__ B,
             const float* __restrict__ bias0, const float* __restrict__ bias1,
             float* __restrict__ C, int M, int N, int K)
{
    __shared__ float As[16 * 68];
    __shared__ float Bs[16 * 68];
    const int tid = threadIdx.x;
    const int tx = tid & 15, ty = tid >> 4;
    const int m0 = blockIdx.y * 64, n0 = blockIdx.x * 64;
    float acc[4][4] = {};
    const int KT = (K + 15) >> 4;

    for (int kt = 0; kt < KT; ++kt) {
        const int k0 = kt << 4;
        __syncthreads();
        for (int l = tid; l < 1024; l += 256) {
            const int mm = l >> 4, kk = l & 15;
            const int kg = k0 + kk;
            As[kk * 68 + mm] = (kg < K) ? A[(size_t)(m0 + mm) * K + kg] : 0.f;
            Bs[kk * 68 + mm] = (kg < K && (n0 + mm) < N)
                                   ? B[(size_t)(n0 + mm) * K + kg] : 0.f;
        }
        __syncthreads();
        #pragma unroll
        for (int kk = 0; kk < 16; ++kk) {
            const float4 av = *(const float4*)&As[kk * 68 + ty * 4];
            const float4 bv = *(const float4*)&Bs[kk * 68 + tx * 4];
            const float a[4] = {av.x, av.y, av.z, av.w};
            const float b[4] = {bv.x, bv.y, bv.z, bv.w};
            #pragma unroll
            for (int i = 0; i < 4; ++i)
                #pragma unroll
                for (int j = 0; j < 4; ++j)
                    acc[i][j] += a[i] * b[j];
        }
    }

    float bj[4];
    #pragma unroll
    for (int j = 0; j < 4; ++j) {
        const int n = n0 + tx * 4 + j;
        float bv = 0.f;
        if (n < N) {
            if (bias0) bv += bias0[n];
            if (bias1) bv += bias1[n];
        }
        bj[j] = bv;
    }
    #pragma unroll
    for (int i = 0; i < 4; ++i) {
        const int m = m0 + ty * 4 + i;
        #pragma unroll
        for (int j = 0; j < 4; ++j) {
            const int n = n0 + tx * 4 + j;
            if (n < N) C[(size_t)m * N + n] = acc[i][j] + bj[j];
        }
    }
}

// ---------------------------------------------------------------------------
// Fused 3-layer pipelined LSTM scan. 768 blocks x 256 threads, 3 blocks/CU.
//   layer = blockIdx>>8, b = blockIdx&255; block owns units u0=4b..4b+3.
//
// ROUND-N CHANGE (spill fix): previous round needed 128 weight floats/thread
// (ih+hh); rocprof showed VGPR_Count=84 -> the allocator spilled most of the
// weight array, and the per-step scratch/L3 reload (~60-100 MB/step) was the
// 8.1 us/slot bottleneck (invisible in FETCH_SIZE which counts HBM only).
// Now:
//  * Registers hold ONLY W_hh: wave w owns unit u0+w; lane ln covers the 16
//    interleaved columns {ln + 64j} for all 4 gates -> 64 floats/thread,
//    guaranteed to fit the 168-reg cap of __launch_bounds__(256,3).
//  * The non-recurrent W_ih*h_in term is computed in a chunked in-block
//    mini-GEMM every CHK=32 steps (LDS-tiled: Wt[16][128], Ht[32][129]),
//    so W_ih streams from L2/L3 once per 32 steps instead of every step.
//    Biases are folded into the chunk result (xgbuf).
//  * Per-step polling is own-layer h(t-1) only; cross-layer coupling happens
//    once per chunk (tagged-quad verified during Ht staging).
// h exchange via per-layer tagged u64 hbuf ((t+1)<<32 | f32bits), agent
// scope, sentinel-word poll + s_sleep backoff. Deps: own-layer all-to-all
// (full residency: 768 = 3/CU exactly) + lower-layer chunk reads.
// ---------------------------------------------------------------------------
__device__ __forceinline__ float sig_(float x) { return 1.f / (1.f + expf(-x)); }

__global__ __launch_bounds__(256, 3)
void lstm_fused(const float* __restrict__ xg,
                const float* __restrict__ Whh0,
                const float* __restrict__ Wih1, const float* __restrict__ Whh1,
                const float* __restrict__ bih1, const float* __restrict__ bhh1,
                const float* __restrict__ Wih2, const float* __restrict__ Whh2,
                const float* __restrict__ bih2, const float* __restrict__ bhh2,
                u64* __restrict__ hbuf0, u64* __restrict__ hbuf1,
                u64* __restrict__ hbuf2, float* __restrict__ hs2)
{
    __shared__ float hprev_lds[HID];        // 4 KB
    __shared__ float gsum[4][4];            // 64 B
    __shared__ float xgbuf[CHK][4][4];      // 2 KB   [tc][unit][gate]
    __shared__ float Wt[16][128];           // 8 KB   ih tile, row = g*4+uloc
    __shared__ float Ht[32 * 129];          // 16.1 KB h_in tile, pad 129 (bank-free)

    const int tid = threadIdx.x;
    const int w = tid >> 6, ln = tid & 63;
    const int layer = blockIdx.x >> 8;
    const int b = blockIdx.x & 255;
    const int u0 = 4 * b;
    const int unit = u0 + w;

    const float* Whh = (layer == 0) ? Whh0 : (layer == 1 ? Whh1 : Whh2);
    const float* Wih = (layer == 1) ? Wih1 : Wih2;                  // unused layer 0
    u64* hbI = (layer == 1) ? hbuf0 : hbuf1;                        // input-h buffer
    u64* hbP = (layer == 0) ? hbuf0 : (layer == 1 ? hbuf1 : hbuf2); // own-layer buffer

    // ---- recurrent weights in registers: 4 gates x 16 interleaved cols ----
    // lane ln covers cols {ln + 64j}; LDS matvec reads then hit bank ln%32
    // for every j (2-way wave64 aliasing = free).
    float Wv[4][16];
    #pragma unroll
    for (int g = 0; g < 4; ++g) {
        const float* rp = Whh + (size_t)(g * HID + unit) * HID + ln;
        #pragma unroll
        for (int j = 0; j < 16; ++j)
            Wv[g][j] = rp[64 * j];
    }

    // per-(gate,unit) bias, folded into the chunk GEMM result (layers 1,2)
    float bias4[4] = {0.f, 0.f, 0.f, 0.f};
    if (layer == 1) {
        #pragma unroll
        for (int g = 0; g < 4; ++g)
            bias4[g] = bih1[g * HID + unit] + bhh1[g * HID + unit];
    } else if (layer == 2) {
        #pragma unroll
        for (int g = 0; g < 4; ++g)
            bias4[g] = bih2[g * HID + unit] + bhh2[g * HID + unit];
    }

    float c = 0.f;   // cell state in wave-0 lanes 0..3
    for (int t = 0; t < TT; ++t) {
        // =============== chunk ih-GEMM (layers 1,2; every CHK steps) =======
        if (layer > 0 && (t & (CHK - 1)) == 0) {
            const int tc = ln & 31, half = ln >> 5;   // MAC mapping
            float acc[4];
            #pragma unroll
            for (int g = 0; g < 4; ++g) acc[g] = (half == 0) ? bias4[g] : 0.f;

            const int wr = tid >> 4;            // Wt staging row (g=wr>>2, uloc=wr&3)
            const int wc = (tid & 15) * 8;      // Wt staging col
            const float* wsrc = Wih + (size_t)((wr >> 2) * HID + u0 + (wr & 3)) * HID + wc;
            const int stc = tid >> 3;           // Ht staging row (tc)
            const int skk = (tid & 7) * 16;     // Ht staging col base

            for (int kt = 0; kt < 8; ++kt) {
                __syncthreads();   // Wt/Ht safe to overwrite
                // stage W_ih tile: 16 rows x 128 cols (coalesced, read-only)
                *(float4*)&Wt[wr][wc]     = *(const float4*)(wsrc + kt * 128);
                *(float4*)&Wt[wr][wc + 4] = *(const float4*)(wsrc + kt * 128 + 4);
                // stage h_in tile: 32 steps x 128 units of tagged u64
                {
                    const u64* src = hbI + (size_t)(t + stc) * HID + kt * 128 + skk;
                    const u64 tag = (u64)(unsigned)(t + stc + 1);
                    u64 v[16];
                    int guard = 0;
                    for (;;) {
                        bool ok = true;
                        #pragma unroll
                        for (int i = 0; i < 16; ++i)
                            v[i] = __hip_atomic_load(src + i, __ATOMIC_RELAXED,
                                                     __HIP_MEMORY_SCOPE_AGENT);
                        #pragma unroll
                        for (int i = 0; i < 16; ++i)
                            ok = ok && ((v[i] >> 32) == tag);
                        if (ok) break;
                        if (++guard > (1 << 22)) break;   // anti-hang bailout
                        __builtin_amdgcn_s_sleep(1);
                    }
                    float* hrow = &Ht[stc * 129 + skk];
                    #pragma unroll
                    for (int i = 0; i < 16; ++i)
                        hrow[i] = __uint_as_float((unsigned)v[i]);
                }
                __syncthreads();
                // MAC: lane = (tc, half); unit = w; 4 gates x 64 ks per tile
                const float* hrow = &Ht[tc * 129 + half * 64];
                #pragma unroll
                for (int kb = 0; kb < 16; ++kb) {
                    const float h0 = hrow[kb * 4 + 0];
                    const float h1 = hrow[kb * 4 + 1];
                    const float h2 = hrow[kb * 4 + 2];
                    const float h3 = hrow[kb * 4 + 3];
                    #pragma unroll
                    for (int g = 0; g < 4; ++g) {
                        const float4 w4 = *(const float4*)&Wt[g * 4 + w][half * 64 + kb * 4];
                        acc[g] += w4.x * h0 + w4.y * h1 + w4.z * h2 + w4.w * h3;
                    }
                }
            }
            // combine k-halves; lanes<32 publish to xgbuf
            #pragma unroll
            for (int g = 0; g < 4; ++g)
                acc[g] += __shfl_xor(acc[g], 32, 64);
            if (ln < 32) {
                #pragma unroll
                for (int g = 0; g < 4; ++g)
                    xgbuf[tc][w][g] = acc[g];
            }
            // visibility to consumers is ordered by barrier (1) below
        }

        // =============== per-step scan ====================================
        // layer-0 x-gates prefetch (pre-poll)
        float add4[4];
        if (layer == 0 && w == 0 && ln < 4) {
            #pragma unroll
            for (int g = 0; g < 4; ++g)
                add4[g] = xg[(size_t)t * G4 + g * HID + u0 + ln];
        }

        // ---- acquire own-layer h(t-1) (block-rotated unit assignment) ----
        const int p4 = 4 * ((tid + b) & 255);
        if (t == 0) {
            *(float4*)&hprev_lds[p4] = make_float4(0.f, 0.f, 0.f, 0.f);
        } else {
            const u64 tagP = (u64)(unsigned)t;      // hbP[t-1] carries tag t
            const u64* pp = hbP + (size_t)(t - 1) * HID + p4;
            u64 vp0 = 0, vp1 = 0, vp2 = 0, vp3 = 0;
            int guard = 0;
            for (;;) {
                vp0 = __hip_atomic_load(pp + 0, __ATOMIC_RELAXED, __HIP_MEMORY_SCOPE_AGENT);
                if ((vp0 >> 32) == tagP) {   // sentinel hit: quad published together
                    vp1 = __hip_atomic_load(pp + 1, __ATOMIC_RELAXED, __HIP_MEMORY_SCOPE_AGENT);
                    vp2 = __hip_atomic_load(pp + 2, __ATOMIC_RELAXED, __HIP_MEMORY_SCOPE_AGENT);
                    vp3 = __hip_atomic_load(pp + 3, __ATOMIC_RELAXED, __HIP_MEMORY_SCOPE_AGENT);
                    if ((vp1 >> 32) == tagP && (vp2 >> 32) == tagP &&
                        (vp3 >> 32) == tagP)
                        break;
                }
                if (++guard > (1 << 22)) break;   // anti-hang bailout
                __builtin_amdgcn_s_sleep(1);      // ~64cy backoff
            }
            *(float4*)&hprev_lds[p4] = make_float4(
                __uint_as_float((unsigned)vp0), __uint_as_float((unsigned)vp1),
                __uint_as_float((unsigned)vp2), __uint_as_float((unsigned)vp3));
        }
        __syncthreads();   // (1) h staged; also orders xgbuf writes -> reads

        // ---- hh matvec: 4 gates x 16 interleaved cols, weights in regs ----
        float a0 = 0.f, a1 = 0.f, a2 = 0.f, a3 = 0.f;
        #pragma unroll
        for (int j = 0; j < 16; ++j) {
            const float h = hprev_lds[ln + 64 * j];
            a0 += Wv[0][j] * h;
            a1 += Wv[1][j] * h;
            a2 += Wv[2][j] * h;
            a3 += Wv[3][j] * h;
        }
        // 64-lane butterfly: full 1024-col dot per gate
        #pragma unroll
        for (int off = 1; off < 64; off <<= 1) {
            a0 += __shfl_xor(a0, off, 64);
            a1 += __shfl_xor(a1, off, 64);
            a2 += __shfl_xor(a2, off, 64);
            a3 += __shfl_xor(a3, off, 64);
        }
        if (ln == 0) {
            gsum[w][0] = a0; gsum[w][1] = a1; gsum[w][2] = a2; gsum[w][3] = a3;
        }
        __syncthreads();   // (2) gate sums exchanged; LDS safe next iter

        // ---- wave 0 lanes 0..3: elementwise + COALESCED quad publish ----
        if (w == 0 && ln < 4) {
            float ad0, ad1, ad2, ad3;
            if (layer == 0) {
                ad0 = add4[0]; ad1 = add4[1]; ad2 = add4[2]; ad3 = add4[3];
            } else {
                const int tc = t & (CHK - 1);
                ad0 = xgbuf[tc][ln][0]; ad1 = xgbuf[tc][ln][1];
                ad2 = xgbuf[tc][ln][2]; ad3 = xgbuf[tc][ln][3];
            }
            const float i_ = sig_(gsum[ln][0] + ad0);
            const float f_ = sig_(gsum[ln][1] + ad1);
            const float g_ = tanhf(gsum[ln][2] + ad2);
            const float o_ = sig_(gsum[ln][3] + ad3);
            c = f_ * c + i_ * g_;
            const float h = o_ * tanhf(c);
            if (layer == 2) hs2[(size_t)t * HID + u0 + ln] = h;
            const u64 pv = (((u64)(unsigned)(t + 1)) << 32) |
                           (u64)__float_as_uint(h);
            __hip_atomic_store(hbP + (size_t)t * HID + u0 + ln, pv,
                               __ATOMIC_RELAXED, __HIP_MEMORY_SCOPE_AGENT);
        }
        // Next iteration's poll gates every consumer on this publish; gsum is
        // rewritten only after the next barrier(1)+matvec, so no extra barrier.
    }
}

// ---------------------------------------------------------------------------
extern "C" void kernel_launch(void* const* d_in, const int* in_sizes, int n_in,
                              void* d_out, int out_size, void* d_ws, size_t ws_size,
                              hipStream_t stream)
{
    (void)in_sizes; (void)n_in; (void)out_size; (void)ws_size;

    const float* pose = (const float*)d_in[0];
    const float* Wih0 = (const float*)d_in[1];
    const float* Whh0 = (const float*)d_in[2];
    const float* bih0 = (const float*)d_in[3];
    const float* bhh0 = (const float*)d_in[4];
    const float* Wih1 = (const float*)d_in[5];
    const float* Whh1 = (const float*)d_in[6];
    const float* bih1 = (const float*)d_in[7];
    const float* bhh1 = (const float*)d_in[8];
    const float* Wih2 = (const float*)d_in[9];
    const float* Whh2 = (const float*)d_in[10];
    const float* bih2 = (const float*)d_in[11];
    const float* bhh2 = (const float*)d_in[12];
    const float* Wout = (const float*)d_in[13];
    float* out = (float*)d_out;

    // Workspace: hbuf0|hbuf1|hbuf2 (3 x 4 MB tagged u64) | xg (8 MB) | hs2 (2 MB)
    char* ws = (char*)d_ws;
    const size_t HB = (size_t)TT * HID * sizeof(u64);
    u64* hbuf0 = (u64*)ws;
    u64* hbuf1 = (u64*)(ws + HB);
    u64* hbuf2 = (u64*)(ws + 2 * HB);
    float* xg  = (float*)(ws + 3 * HB);
    float* hs2 = (float*)(ws + 3 * HB + (size_t)TT * G4 * sizeof(float));

    hipMemsetAsync(hbuf0, 0, 3 * HB, stream);

    const dim3 blk(256);
    // layer-0 x-gates: [512,85] x [85,4096]^T (+ both biases)
    gemm_nt<<<dim3(G4 / 64, TT / 64), blk, 0, stream>>>(
        pose, Wih0, bih0, bhh0, xg, TT, G4, INDIM);
    // fused pipelined 3-layer scan
    lstm_fused<<<dim3(768), blk, 0, stream>>>(
        xg, Whh0, Wih1, Whh1, bih1, bhh1, Wih2, Whh2, bih2, bhh2,
        hbuf0, hbuf1, hbuf2, hs2);
    // output projection: [512,1024] x [1024,20670]^T
    gemm_nt<<<dim3((NOUT + 63) / 64, TT / 64), blk, 0, stream>>>(
        hs2, Wout, nullptr, nullptr, out, TT, NOUT, HID);
}